// Round 3
// baseline (241.103 us; speedup 1.0000x reference)
//
#include <hip/hip_runtime.h>
#include <math.h>

// Problem shape (from reference setup_inputs): B=4096, D=2048, C=1000, N=C+B=5096.
#define D_DIM 2048
#define GAP_TAU 0.02f   // per-logit |fp16_approx - fp32_exact| bound (>20 sigma)

typedef _Float16 f16;
typedef f16 f16x8 __attribute__((ext_vector_type(8)));
typedef float f32x4 __attribute__((ext_vector_type(4)));

// ---------------------------------------------------------------------------
// Virtual concat: supports = [W (C rows); z (B rows)], each row D_DIM floats.
// ---------------------------------------------------------------------------
__device__ __forceinline__ const float* support_row(int i, const float* __restrict__ W,
                                                    const float* __restrict__ z, int C) {
  return (i < C) ? (W + (size_t)i * D_DIM) : (z + (size_t)(i - C) * D_DIM);
}

// async global->LDS, 16B per lane. LDS dest = wave-uniform base + lane*16.
__device__ __forceinline__ void async_ld16(const f16* g, f16* l) {
  __builtin_amdgcn_global_load_lds((const __attribute__((address_space(1))) void*)g,
                                   (__attribute__((address_space(3))) void*)l, 16, 0, 0);
}

// ---------------------------------------------------------------------------
// prep: suph[i][:] = f16(support_row(i)) for i < Nsup, zeros for pad rows;
// norms[i] = ||support_row(i)||_2.  One block (256 thr) per padded row;
// thread t owns dims t*8..t*8+7.
// ---------------------------------------------------------------------------
__global__ __launch_bounds__(256) void prep_kernel(const float* __restrict__ z,
                                                   const float* __restrict__ W,
                                                   int C, int Nsup, int Mpad,
                                                   f16* __restrict__ suph,
                                                   float* __restrict__ norms) {
  const int i = blockIdx.x;
  const int t = threadIdx.x;
  f16* dst = suph + (size_t)i * D_DIM + t * 8;
  if (i >= Nsup) {
    f16x8 zz = {0, 0, 0, 0, 0, 0, 0, 0};
    *(f16x8*)dst = zz;
    return;
  }
  const float* src = support_row(i, W, z, C) + t * 8;
  const float4 a = *(const float4*)src;
  const float4 b = *(const float4*)(src + 4);
  f16x8 v;
  v[0] = (f16)a.x; v[1] = (f16)a.y; v[2] = (f16)a.z; v[3] = (f16)a.w;
  v[4] = (f16)b.x; v[5] = (f16)b.y; v[6] = (f16)b.z; v[7] = (f16)b.w;
  *(f16x8*)dst = v;

  float ss = a.x * a.x;
  ss = fmaf(a.y, a.y, ss); ss = fmaf(a.z, a.z, ss); ss = fmaf(a.w, a.w, ss);
  ss = fmaf(b.x, b.x, ss); ss = fmaf(b.y, b.y, ss); ss = fmaf(b.z, b.z, ss);
  ss = fmaf(b.w, b.w, ss);
  __shared__ float red[256];
  red[t] = ss;
  __syncthreads();
  for (int k = 128; k > 0; k >>= 1) {
    if (t < k) red[t] += red[t + k];
    __syncthreads();
  }
  if (t == 0) norms[i] = sqrtf(red[0]);
}

// ---------------------------------------------------------------------------
// fp16 MFMA GEMM (m97 structure): Cmat[M,N] = A[M,K] @ B[N,K]^T, fp32 out.
// 128x128 tile, BK=32, 256 threads = 4 waves (2x2), each wave 64x64 = 4x4
// MFMA tiles of 16x16x32. Staging via global_load_lds width=16 (4 issues per
// thread per K-iter). A and B must be padded to multiples of 128 rows (all
// loads unguarded); only C stores are predicated (r < Mstore, c < Nstore).
// LDS tiles row-major [row][32 f16] with 16B-chunk XOR swizzle key (row>>1)&3
// -> 2-way bank aliasing on ds_read_b128 (free on CDNA4, m136); staging
// writes are lane-sequential -> conflict-free.
// ---------------------------------------------------------------------------
#define TM 128
#define TN 128

__global__ __launch_bounds__(256) void gemm_f16(const f16* __restrict__ A,
                                                const f16* __restrict__ B,
                                                float* __restrict__ Cmat,
                                                int K, int ldc, int Mstore, int Nstore) {
  __shared__ __align__(16) f16 As[TM * 32];  // 8 KB
  __shared__ __align__(16) f16 Bs[TN * 32];  // 8 KB

  const int tid = threadIdx.x;
  const int wave = tid >> 6;
  const int lane = tid & 63;
  const int quad = lane >> 4;
  const int lr = lane & 15;
  const int row0 = blockIdx.x * TM;
  const int col0 = blockIdx.y * TN;
  const int wr = (wave >> 1) * 64;
  const int wc = (wave & 1) * 64;

  // staging: instruction (wave, s) covers LDS 16B-chunks [(wave*2+s)*64, +64),
  // lane covers chunk i; physical (row=i>>2, cp=i&3) holds global chunk
  // cg = cp ^ ((row>>1)&3).
  const f16* ag[2];
  const f16* bg[2];
  f16* al[2];
  f16* bl[2];
#pragma unroll
  for (int s = 0; s < 2; s++) {
    const int i = (wave * 2 + s) * 64 + lane;
    const int row = i >> 2;
    const int cg = (i & 3) ^ ((row >> 1) & 3);
    ag[s] = A + (size_t)(row0 + row) * K + cg * 8;
    bg[s] = B + (size_t)(col0 + row) * K + cg * 8;
    al[s] = As + (wave * 2 + s) * 512;  // wave-uniform LDS base (64 chunks * 8 f16)
    bl[s] = Bs + (wave * 2 + s) * 512;
  }

  // fragment read offsets (f16 elems): A[m=lr][k=quad*8+j] at row m, chunk quad
  int aoff[4], boff[4];
#pragma unroll
  for (int tq = 0; tq < 4; tq++) {
    const int ra = wr + tq * 16 + lr;
    aoff[tq] = ra * 32 + (quad ^ ((ra >> 1) & 3)) * 8;
    const int rb = wc + tq * 16 + lr;
    boff[tq] = rb * 32 + (quad ^ ((rb >> 1) & 3)) * 8;
  }

  f32x4 acc[4][4];
#pragma unroll
  for (int i = 0; i < 4; i++)
#pragma unroll
    for (int j = 0; j < 4; j++) {
      acc[i][j][0] = 0.f; acc[i][j][1] = 0.f; acc[i][j][2] = 0.f; acc[i][j][3] = 0.f;
    }

  for (int k0 = 0; k0 < K; k0 += 32) {
#pragma unroll
    for (int s = 0; s < 2; s++) {
      async_ld16(ag[s] + k0, al[s]);
      async_ld16(bg[s] + k0, bl[s]);
    }
    __syncthreads();  // drains vmcnt -> tile visible

    f16x8 af[4], bf[4];
#pragma unroll
    for (int i = 0; i < 4; i++) af[i] = *(const f16x8*)(As + aoff[i]);
#pragma unroll
    for (int i = 0; i < 4; i++) bf[i] = *(const f16x8*)(Bs + boff[i]);
#pragma unroll
    for (int i = 0; i < 4; i++)
#pragma unroll
      for (int j = 0; j < 4; j++)
        acc[i][j] = __builtin_amdgcn_mfma_f32_16x16x32_f16(af[i], bf[j], acc[i][j], 0, 0, 0);
    __syncthreads();  // reads done before next iter's staging
  }

  // epilogue: C/D layout col=lane&15, row=quad*4+reg
#pragma unroll
  for (int i = 0; i < 4; i++) {
#pragma unroll
    for (int reg = 0; reg < 4; reg++) {
      const int r = row0 + wr + i * 16 + quad * 4 + reg;
      if (r >= Mstore) continue;
#pragma unroll
      for (int j = 0; j < 4; j++) {
        const int c = col0 + wc + j * 16 + lr;
        if (c < Nstore) Cmat[(size_t)r * ldc + c] = acc[i][j][reg];
      }
    }
  }
}

// ---------------------------------------------------------------------------
// row_stats fused: per support row, argmax (lowest index ties) + top-2 gap +
// entropy from APPROX logits; rows with gap <= 2*TAU get exact fp32 argmax
// repair over candidate classes (logit >= max - 2*TAU — provably contains the
// true argmax). One wave per row, 4 rows per block, shuffle reductions.
// ---------------------------------------------------------------------------
__global__ __launch_bounds__(256) void row_stats(const float* __restrict__ logits, int Cc,
                                                 const float* __restrict__ z,
                                                 const float* __restrict__ W,
                                                 int Nsup,
                                                 float* __restrict__ ent,
                                                 int* __restrict__ yhat) {
  const int wave = threadIdx.x >> 6;
  const int lane = threadIdx.x & 63;
  const int r = blockIdx.x * 4 + wave;
  if (r >= Nsup) return;
  const float* row = logits + (size_t)r * Cc;

  float v[16];
#pragma unroll
  for (int j = 0; j < 16; j++) {
    const int c = lane + j * 64;
    v[j] = (c < Cc) ? row[c] : -3.0e38f;
  }
  // lane-local top-2 (+ index of max; ascending c -> first hit is lowest idx)
  float m1 = -3.0e38f, m2 = -3.0e38f;
  int i1 = 0x7fffffff;
#pragma unroll
  for (int j = 0; j < 16; j++) {
    const float x = v[j];
    if (x > m1) { m2 = m1; m1 = x; i1 = lane + j * 64; }
    else if (x > m2) { m2 = x; }       // x == m1 lands here -> gap 0
  }
  // wave merge
#pragma unroll
  for (int s = 1; s < 64; s <<= 1) {
    const float om1 = __shfl_xor(m1, s);
    const float om2 = __shfl_xor(m2, s);
    const int oi1 = __shfl_xor(i1, s);
    if (om1 > m1) { m2 = fmaxf(m1, om2); m1 = om1; i1 = oi1; }
    else if (om1 < m1) { m2 = fmaxf(m2, om1); }
    else { i1 = min(i1, oi1); m2 = m1; }  // duplicate max across segments
  }

  // entropy sums (stable, from approx logits — only consumed if a class
  // exceeds K members, which requires count > 100; max observed ~20)
  float s1 = 0.f, s2 = 0.f;
#pragma unroll
  for (int j = 0; j < 16; j++) {
    const int c = lane + j * 64;
    if (c < Cc) {
      const float d = v[j] - m1;
      const float e = expf(d);
      s1 += e;
      s2 = fmaf(d, e, s2);
    }
  }
#pragma unroll
  for (int s = 1; s < 64; s <<= 1) {
    s1 += __shfl_xor(s1, s);
    s2 += __shfl_xor(s2, s);
  }

  // ambiguous-argmax repair with exact fp32 dots
  if (m1 - m2 <= 2.0f * GAP_TAU) {
    const float thresh = m1 - 2.0f * GAP_TAU;
    const float* srow = support_row(r, W, z, Cc);
    float best = -3.0e38f;
    int bi = 0x7fffffff;
#pragma unroll
    for (int j = 0; j < 16; j++) {
      const int c = lane + j * 64;
      unsigned long long mask = __ballot(c < Cc && v[j] >= thresh);
      while (mask) {
        const int src = __ffsll((long long)mask) - 1;
        mask &= mask - 1;
        const int cc = src + j * 64;
        const float* wrow = W + (size_t)cc * D_DIM;
        float s = 0.f;
        for (int d = lane; d < D_DIM; d += 64) s = fmaf(srow[d], wrow[d], s);
#pragma unroll
        for (int t = 1; t < 64; t <<= 1) s += __shfl_xor(s, t);
        if (s > best || (s == best && cc < bi)) { best = s; bi = cc; }
      }
    }
    i1 = bi;
  }

  if (lane == 0) {
    ent[r] = logf(s1) - s2 / s1;
    yhat[r] = i1;
  }
}

// ---------------------------------------------------------------------------
// accum fused: per class c — gather members (yhat==c) into LDS, top-K select
// by entropy if count > K (never in practice: mean count ~5, K=100), sum
// normalized member rows, column-normalize, write f16 weights row directly.
// Pad classes (c >= C) write zero rows. Thread t owns dims t*8..t*8+7.
// ---------------------------------------------------------------------------
#define MAXLIST 1024

__global__ __launch_bounds__(256) void accum_kernel(const float* __restrict__ z,
                                                    const float* __restrict__ W,
                                                    int C, int Nsup,
                                                    const int* __restrict__ yhat,
                                                    const float* __restrict__ ent,
                                                    const float* __restrict__ norms,
                                                    const int* __restrict__ Kp,
                                                    f16* __restrict__ wh) {
  const int c = blockIdx.x;
  const int t = threadIdx.x;
  f16* dst = wh + (size_t)c * D_DIM + t * 8;
  if (c >= C) {
    f16x8 zz = {0, 0, 0, 0, 0, 0, 0, 0};
    *(f16x8*)dst = zz;
    return;
  }

  __shared__ int list[MAXLIST];
  __shared__ unsigned char sel[MAXLIST];
  __shared__ int cnt;
  __shared__ float red[256];
  if (t == 0) cnt = 0;
  __syncthreads();
  for (int i = t; i < Nsup; i += 256) {
    if (yhat[i] == c) {
      const int p = atomicAdd(&cnt, 1);
      if (p < MAXLIST) list[p] = i;
    }
  }
  __syncthreads();
  const int K = *Kp;
  const int n = min(cnt, MAXLIST);
  if (cnt <= K) {
    for (int j = t; j < n; j += 256) sel[j] = 1;
  } else {
    // exact rank-based K-smallest-entropy (top_k tie semantics: lower index)
    for (int j = t; j < n; j += 256) {
      const int si = list[j];
      const float ei = ent[si];
      int rank = 0;
      for (int l = 0; l < n; l++) {
        const int sl = list[l];
        const float el = ent[sl];
        rank += (el < ei || (el == ei && sl < si)) ? 1 : 0;
      }
      sel[j] = (rank < K) ? 1 : 0;
    }
  }
  __syncthreads();

  float a[8];
#pragma unroll
  for (int q = 0; q < 8; q++) a[q] = 0.f;
  for (int j = 0; j < n; j++) {
    if (!sel[j]) continue;
    const int si = list[j];
    const float* row = support_row(si, W, z, C) + t * 8;
    const float inv = 1.0f / fmaxf(norms[si], 1e-12f);
    const float4 r0 = *(const float4*)row;
    const float4 r1 = *(const float4*)(row + 4);
    a[0] = fmaf(r0.x, inv, a[0]); a[1] = fmaf(r0.y, inv, a[1]);
    a[2] = fmaf(r0.z, inv, a[2]); a[3] = fmaf(r0.w, inv, a[3]);
    a[4] = fmaf(r1.x, inv, a[4]); a[5] = fmaf(r1.y, inv, a[5]);
    a[6] = fmaf(r1.z, inv, a[6]); a[7] = fmaf(r1.w, inv, a[7]);
  }

  float ss = 0.f;
#pragma unroll
  for (int q = 0; q < 8; q++) ss = fmaf(a[q], a[q], ss);
  red[t] = ss;
  __syncthreads();
  for (int k = 128; k > 0; k >>= 1) {
    if (t < k) red[t] += red[t + k];
    __syncthreads();
  }
  const float invn = 1.0f / fmaxf(sqrtf(red[0]), 1e-12f);
  f16x8 o;
#pragma unroll
  for (int q = 0; q < 8; q++) o[q] = (f16)(a[q] * invn);
  *(f16x8*)dst = o;
}

// ---------------------------------------------------------------------------
// Launch
// ---------------------------------------------------------------------------
extern "C" void kernel_launch(void* const* d_in, const int* in_sizes, int n_in,
                              void* d_out, int out_size, void* d_ws, size_t ws_size,
                              hipStream_t stream) {
  const float* z = (const float*)d_in[0];
  const float* W = (const float*)d_in[1];
  const int* Kp = (const int*)d_in[2];

  const int D = D_DIM;
  const int B = in_sizes[0] / D;   // 4096
  const int C = in_sizes[1] / D;   // 1000
  const int Nsup = C + B;          // 5096
  const int Mpad = (Nsup + TM - 1) / TM * TM;  // 5120
  const int Npad = (C + TN - 1) / TN * TN;     // 1024

  char* ws = (char*)d_ws;
  size_t off = 0;
  auto alloc = [&](size_t bytes) -> void* {
    void* p = ws + off;
    off += (bytes + 255) & ~(size_t)255;
    return p;
  };

  f16*   suph   = (f16*)alloc((size_t)Mpad * D * sizeof(f16));    // ~21.0 MB (W rows, z rows, 0-pad)
  f16*   wh     = (f16*)alloc((size_t)Npad * D * sizeof(f16));    // ~4.2 MB
  float* logits = (float*)alloc((size_t)Nsup * C * sizeof(float)); // ~20.4 MB
  float* ent    = (float*)alloc((size_t)Nsup * sizeof(float));
  int*   yhat   = (int*)alloc((size_t)Nsup * sizeof(int));
  float* norms  = (float*)alloc((size_t)Nsup * sizeof(float));
  (void)ws_size;

  // 1) f16 support matrix (padded) + norms
  prep_kernel<<<Mpad, 256, 0, stream>>>(z, W, C, Nsup, Mpad, suph, norms);

  // 2) logits[Nsup, C] ~= supports @ W^T  (fp16 MFMA; B = first 1024 suph rows,
  //    cols 1000..1023 are z-garbage but never stored)
  {
    dim3 grid(Mpad / TM, Npad / TN);
    gemm_f16<<<grid, 256, 0, stream>>>(suph, suph, logits, D, C, Nsup, C);
  }

  // 3) argmax + entropy + exact repair of ambiguous rows
  row_stats<<<(Nsup + 3) / 4, 256, 0, stream>>>(logits, C, z, W, Nsup, ent, yhat);

  // 4) per-class gather/select/accumulate/normalize -> wh[Npad, D] f16
  accum_kernel<<<Npad, 256, 0, stream>>>(z, W, C, Nsup, yhat, ent, norms, Kp, wh);

  // 5) out[B, C] = z @ weights^T  (A = z rows of suph, exact 32x128)
  {
    dim3 grid(B / TM, Npad / TN);
    gemm_f16<<<grid, 256, 0, stream>>>(suph + (size_t)C * D, wh, (float*)d_out, D, C, B, C);
  }
}

// Round 4
// 223.387 us; speedup vs baseline: 1.0793x; 1.0793x over previous
//
#include <hip/hip_runtime.h>
#include <math.h>

// Problem shape (from reference setup_inputs): B=4096, D=2048, C=1000, N=C+B=5096.
#define D_DIM 2048
#define GAP_TAU 0.02f   // per-logit |approx - fp32_exact| bound (>8 sigma incl. split-add)

typedef _Float16 f16;
typedef f16 f16x8 __attribute__((ext_vector_type(8)));
typedef float f32x4 __attribute__((ext_vector_type(4)));

__device__ __forceinline__ const float* support_row(int i, const float* __restrict__ W,
                                                    const float* __restrict__ z, int C) {
  return (i < C) ? (W + (size_t)i * D_DIM) : (z + (size_t)(i - C) * D_DIM);
}

// async global->LDS, 16B per lane. LDS dest = wave-uniform base + lane*16.
__device__ __forceinline__ void async_ld16(const f16* g, f16* l) {
  __builtin_amdgcn_global_load_lds((const __attribute__((address_space(1))) void*)g,
                                   (__attribute__((address_space(3))) void*)l, 16, 0, 0);
}

// ---------------------------------------------------------------------------
// prep: suph[i][:] = f16(support_row(i)) (zeros for pad rows); norms[i] = ||row||.
// One wave per row (4 rows/block), shuffle-only reduction (no barriers).
// Lane covers 8 floats at lane*8 + pass*512, 4 passes.
// ---------------------------------------------------------------------------
__global__ __launch_bounds__(256) void prep_kernel(const float* __restrict__ z,
                                                   const float* __restrict__ W,
                                                   int C, int Nsup,
                                                   f16* __restrict__ suph,
                                                   float* __restrict__ norms) {
  const int wave = threadIdx.x >> 6;
  const int lane = threadIdx.x & 63;
  const int i = blockIdx.x * 4 + wave;
  f16* dst = suph + (size_t)i * D_DIM;
  if (i >= Nsup) {
    f16x8 zz = {0, 0, 0, 0, 0, 0, 0, 0};
#pragma unroll
    for (int p = 0; p < 4; p++) *(f16x8*)(dst + p * 512 + lane * 8) = zz;
    return;
  }
  const float* src = support_row(i, W, z, C);
  float ss = 0.f;
#pragma unroll
  for (int p = 0; p < 4; p++) {
    const int off = p * 512 + lane * 8;
    const float4 a = *(const float4*)(src + off);
    const float4 b = *(const float4*)(src + off + 4);
    f16x8 v;
    v[0] = (f16)a.x; v[1] = (f16)a.y; v[2] = (f16)a.z; v[3] = (f16)a.w;
    v[4] = (f16)b.x; v[5] = (f16)b.y; v[6] = (f16)b.z; v[7] = (f16)b.w;
    *(f16x8*)(dst + off) = v;
    ss = fmaf(a.x, a.x, ss); ss = fmaf(a.y, a.y, ss);
    ss = fmaf(a.z, a.z, ss); ss = fmaf(a.w, a.w, ss);
    ss = fmaf(b.x, b.x, ss); ss = fmaf(b.y, b.y, ss);
    ss = fmaf(b.z, b.z, ss); ss = fmaf(b.w, b.w, ss);
  }
#pragma unroll
  for (int s = 1; s < 64; s <<= 1) ss += __shfl_xor(ss, s);
  if (lane == 0) norms[i] = sqrtf(ss);
}

// ---------------------------------------------------------------------------
// fp16 MFMA GEMM, split-K=2 via blockIdx.z: P[z] = A[:, z*Ks:(z+1)*Ks] @ B^T.
// 128x128 tile, BK=32, 256 threads = 4 waves (2x2), wave = 64x64 = 4x4 MFMA
// 16x16x32. global_load_lds width=16 staging (verified conflict-free swizzle:
// 16B-chunk XOR key (row>>1)&3). A/B padded to x128 rows; stores unpredicated
// into padded partial buffers.
// ---------------------------------------------------------------------------
#define TM 128
#define TN 128

__global__ __launch_bounds__(256) void gemm_f16(const f16* __restrict__ A,
                                                const f16* __restrict__ B,
                                                float* __restrict__ P,
                                                int K, int Ks, long partStride, int ldc) {
  __shared__ __align__(16) f16 As[TM * 32];
  __shared__ __align__(16) f16 Bs[TN * 32];

  const int tid = threadIdx.x;
  const int wave = tid >> 6;
  const int lane = tid & 63;
  const int quad = lane >> 4;
  const int lr = lane & 15;
  const int row0 = blockIdx.x * TM;
  const int col0 = blockIdx.y * TN;
  const int kz = blockIdx.z;
  const int kbase = kz * Ks;
  const int wr = (wave >> 1) * 64;
  const int wc = (wave & 1) * 64;

  const f16* ag[2];
  const f16* bg[2];
  f16* al[2];
  f16* bl[2];
#pragma unroll
  for (int s = 0; s < 2; s++) {
    const int i = (wave * 2 + s) * 64 + lane;
    const int row = i >> 2;
    const int cg = (i & 3) ^ ((row >> 1) & 3);
    ag[s] = A + (size_t)(row0 + row) * K + kbase + cg * 8;
    bg[s] = B + (size_t)(col0 + row) * K + kbase + cg * 8;
    al[s] = As + (wave * 2 + s) * 512;
    bl[s] = Bs + (wave * 2 + s) * 512;
  }

  int aoff[4], boff[4];
#pragma unroll
  for (int tq = 0; tq < 4; tq++) {
    const int ra = wr + tq * 16 + lr;
    aoff[tq] = ra * 32 + (quad ^ ((ra >> 1) & 3)) * 8;
    const int rb = wc + tq * 16 + lr;
    boff[tq] = rb * 32 + (quad ^ ((rb >> 1) & 3)) * 8;
  }

  f32x4 acc[4][4];
#pragma unroll
  for (int i = 0; i < 4; i++)
#pragma unroll
    for (int j = 0; j < 4; j++) {
      acc[i][j][0] = 0.f; acc[i][j][1] = 0.f; acc[i][j][2] = 0.f; acc[i][j][3] = 0.f;
    }

  for (int k0 = 0; k0 < Ks; k0 += 32) {
#pragma unroll
    for (int s = 0; s < 2; s++) {
      async_ld16(ag[s] + k0, al[s]);
      async_ld16(bg[s] + k0, bl[s]);
    }
    __syncthreads();

    f16x8 af[4], bf[4];
#pragma unroll
    for (int i = 0; i < 4; i++) af[i] = *(const f16x8*)(As + aoff[i]);
#pragma unroll
    for (int i = 0; i < 4; i++) bf[i] = *(const f16x8*)(Bs + boff[i]);
#pragma unroll
    for (int i = 0; i < 4; i++)
#pragma unroll
      for (int j = 0; j < 4; j++)
        acc[i][j] = __builtin_amdgcn_mfma_f32_16x16x32_f16(af[i], bf[j], acc[i][j], 0, 0, 0);
    __syncthreads();
  }

  float* out = P + (size_t)kz * partStride;
#pragma unroll
  for (int i = 0; i < 4; i++)
#pragma unroll
    for (int reg = 0; reg < 4; reg++) {
      const int r = row0 + wr + i * 16 + quad * 4 + reg;
#pragma unroll
      for (int j = 0; j < 4; j++) {
        const int c = col0 + wc + j * 16 + lr;
        out[(size_t)r * ldc + c] = acc[i][j][reg];
      }
    }
}

// ---------------------------------------------------------------------------
// row_stats: logits row = P0 + P1 (split-K add fused). Argmax (lowest-index
// ties) + top-2 gap + entropy; ambiguous rows (gap <= 2*TAU) repaired with
// exact fp32 dots over candidate classes. One wave per row, 4 rows/block.
// ---------------------------------------------------------------------------
__global__ __launch_bounds__(256) void row_stats(const float* __restrict__ P,
                                                 long partStride, int ldp, int Cc,
                                                 const float* __restrict__ z,
                                                 const float* __restrict__ W,
                                                 int Nsup,
                                                 float* __restrict__ ent,
                                                 int* __restrict__ yhat) {
  const int wave = threadIdx.x >> 6;
  const int lane = threadIdx.x & 63;
  const int r = blockIdx.x * 4 + wave;
  if (r >= Nsup) return;
  const float* r0 = P + (size_t)r * ldp;
  const float* r1 = r0 + partStride;

  float v[16];
#pragma unroll
  for (int j = 0; j < 16; j++) {
    const int c = lane + j * 64;
    v[j] = (c < Cc) ? (r0[c] + r1[c]) : -3.0e38f;
  }
  float m1 = -3.0e38f, m2 = -3.0e38f;
  int i1 = 0x7fffffff;
#pragma unroll
  for (int j = 0; j < 16; j++) {
    const float x = v[j];
    if (x > m1) { m2 = m1; m1 = x; i1 = lane + j * 64; }
    else if (x > m2) { m2 = x; }   // x == m1 lands here -> gap 0
  }
#pragma unroll
  for (int s = 1; s < 64; s <<= 1) {
    const float om1 = __shfl_xor(m1, s);
    const float om2 = __shfl_xor(m2, s);
    const int oi1 = __shfl_xor(i1, s);
    if (om1 > m1) { m2 = fmaxf(m1, om2); m1 = om1; i1 = oi1; }
    else if (om1 < m1) { m2 = fmaxf(m2, om1); }
    else { i1 = min(i1, oi1); m2 = m1; }
  }

  float s1 = 0.f, s2 = 0.f;
#pragma unroll
  for (int j = 0; j < 16; j++) {
    const int c = lane + j * 64;
    if (c < Cc) {
      const float d = v[j] - m1;
      const float e = expf(d);
      s1 += e;
      s2 = fmaf(d, e, s2);
    }
  }
#pragma unroll
  for (int s = 1; s < 64; s <<= 1) {
    s1 += __shfl_xor(s1, s);
    s2 += __shfl_xor(s2, s);
  }

  if (m1 - m2 <= 2.0f * GAP_TAU) {
    const float thresh = m1 - 2.0f * GAP_TAU;
    const float* srow = support_row(r, W, z, Cc);
    float best = -3.0e38f;
    int bi = 0x7fffffff;
#pragma unroll
    for (int j = 0; j < 16; j++) {
      const int c = lane + j * 64;
      unsigned long long mask = __ballot(c < Cc && v[j] >= thresh);
      while (mask) {
        const int src = __ffsll((long long)mask) - 1;
        mask &= mask - 1;
        const int cc = src + j * 64;
        const float* wrow = W + (size_t)cc * D_DIM;
        float s = 0.f;
        for (int d = lane; d < D_DIM; d += 64) s = fmaf(srow[d], wrow[d], s);
#pragma unroll
        for (int t = 1; t < 64; t <<= 1) s += __shfl_xor(s, t);
        if (s > best || (s == best && cc < bi)) { best = s; bi = cc; }
      }
    }
    i1 = bi;
  }

  if (lane == 0) {
    ent[r] = logf(s1) - s2 / s1;
    yhat[r] = i1;
  }
}

// ---------------------------------------------------------------------------
// accum: per class — gather members into LDS, top-K by entropy if count > K
// (never in practice: mean ~5, K=100), sum normalized rows, column-normalize,
// write f16 weights row. Pad classes write zeros. Thread t owns dims t*8..+7.
// ---------------------------------------------------------------------------
#define MAXLIST 1024

__global__ __launch_bounds__(256) void accum_kernel(const float* __restrict__ z,
                                                    const float* __restrict__ W,
                                                    int C, int Nsup,
                                                    const int* __restrict__ yhat,
                                                    const float* __restrict__ ent,
                                                    const float* __restrict__ norms,
                                                    const int* __restrict__ Kp,
                                                    f16* __restrict__ wh) {
  const int c = blockIdx.x;
  const int t = threadIdx.x;
  f16* dst = wh + (size_t)c * D_DIM + t * 8;
  if (c >= C) {
    f16x8 zz = {0, 0, 0, 0, 0, 0, 0, 0};
    *(f16x8*)dst = zz;
    return;
  }

  __shared__ int list[MAXLIST];
  __shared__ unsigned char sel[MAXLIST];
  __shared__ int cnt;
  __shared__ float red[256];
  if (t == 0) cnt = 0;
  __syncthreads();
  for (int i = t; i < Nsup; i += 256) {
    if (yhat[i] == c) {
      const int p = atomicAdd(&cnt, 1);
      if (p < MAXLIST) list[p] = i;
    }
  }
  __syncthreads();
  const int K = *Kp;
  const int n = min(cnt, MAXLIST);
  if (cnt <= K) {
    for (int j = t; j < n; j += 256) sel[j] = 1;
  } else {
    for (int j = t; j < n; j += 256) {
      const int si = list[j];
      const float ei = ent[si];
      int rank = 0;
      for (int l = 0; l < n; l++) {
        const int sl = list[l];
        const float el = ent[sl];
        rank += (el < ei || (el == ei && sl < si)) ? 1 : 0;
      }
      sel[j] = (rank < K) ? 1 : 0;
    }
  }
  __syncthreads();

  float a[8];
#pragma unroll
  for (int q = 0; q < 8; q++) a[q] = 0.f;
  for (int j = 0; j < n; j++) {
    if (!sel[j]) continue;
    const int si = list[j];
    const float* row = support_row(si, W, z, C) + t * 8;
    const float inv = 1.0f / fmaxf(norms[si], 1e-12f);
    const float4 p0 = *(const float4*)row;
    const float4 p1 = *(const float4*)(row + 4);
    a[0] = fmaf(p0.x, inv, a[0]); a[1] = fmaf(p0.y, inv, a[1]);
    a[2] = fmaf(p0.z, inv, a[2]); a[3] = fmaf(p0.w, inv, a[3]);
    a[4] = fmaf(p1.x, inv, a[4]); a[5] = fmaf(p1.y, inv, a[5]);
    a[6] = fmaf(p1.z, inv, a[6]); a[7] = fmaf(p1.w, inv, a[7]);
  }

  float ss = 0.f;
#pragma unroll
  for (int q = 0; q < 8; q++) ss = fmaf(a[q], a[q], ss);
  red[t] = ss;
  __syncthreads();
  for (int k = 128; k > 0; k >>= 1) {
    if (t < k) red[t] += red[t + k];
    __syncthreads();
  }
  const float invn = 1.0f / fmaxf(sqrtf(red[0]), 1e-12f);
  f16x8 o;
#pragma unroll
  for (int q = 0; q < 8; q++) o[q] = (f16)(a[q] * invn);
  *(f16x8*)dst = o;
}

// ---------------------------------------------------------------------------
// reduce_out: out[r][c] = Q0[r][c] + Q1[r][c], c < Ncols. One block per row.
// ---------------------------------------------------------------------------
__global__ __launch_bounds__(256) void reduce_out(const float* __restrict__ Q,
                                                  long partStride, int ldq,
                                                  float* __restrict__ out, int Ncols) {
  const int r = blockIdx.x;
  const float* q0 = Q + (size_t)r * ldq;
  const float* q1 = q0 + partStride;
  float* o = out + (size_t)r * Ncols;
  for (int c = threadIdx.x; c < Ncols; c += 256) o[c] = q0[c] + q1[c];
}

// ---------------------------------------------------------------------------
// Launch
// ---------------------------------------------------------------------------
extern "C" void kernel_launch(void* const* d_in, const int* in_sizes, int n_in,
                              void* d_out, int out_size, void* d_ws, size_t ws_size,
                              hipStream_t stream) {
  const float* z = (const float*)d_in[0];
  const float* W = (const float*)d_in[1];
  const int* Kp = (const int*)d_in[2];

  const int D = D_DIM;
  const int B = in_sizes[0] / D;   // 4096
  const int C = in_sizes[1] / D;   // 1000
  const int Nsup = C + B;          // 5096
  const int Mpad = (Nsup + TM - 1) / TM * TM;  // 5120
  const int Npad = (C + TN - 1) / TN * TN;     // 1024

  char* ws = (char*)d_ws;
  size_t off = 0;
  auto alloc = [&](size_t bytes) -> void* {
    void* p = ws + off;
    off += (bytes + 255) & ~(size_t)255;
    return p;
  };

  const long pStride1 = (long)Mpad * Npad;          // 5.24M floats per half
  const long pStride2 = (long)B * Npad;             // 4.19M floats per half

  f16*   suph  = (f16*)alloc((size_t)Mpad * D * sizeof(f16));        // ~21.0 MB
  f16*   wh    = (f16*)alloc((size_t)Npad * D * sizeof(f16));        // ~4.2 MB
  float* P     = (float*)alloc((size_t)2 * pStride1 * sizeof(float)); // ~41.9 MB (Q aliases)
  float* ent   = (float*)alloc((size_t)Nsup * sizeof(float));
  int*   yhat  = (int*)alloc((size_t)Nsup * sizeof(int));
  float* norms = (float*)alloc((size_t)Nsup * sizeof(float));
  float* Q     = P;  // reuse: P fully consumed by row_stats before gemm2 writes Q
  (void)ws_size;

  // 1) f16 support matrix (padded) + norms — wave per row, no barriers
  prep_kernel<<<Mpad / 4, 256, 0, stream>>>(z, W, C, Nsup, suph, norms);

  // 2) logit partials: P[z] = supports @ W^T over K-half z   (640 blocks)
  {
    dim3 grid(Mpad / TM, Npad / TN, 2);
    gemm_f16<<<grid, 256, 0, stream>>>(suph, suph, P, D, D / 2, pStride1, Npad);
  }

  // 3) argmax + entropy (+ split-K add fused) + exact repair of ambiguous rows
  row_stats<<<(Nsup + 3) / 4, 256, 0, stream>>>(P, pStride1, Npad, C, z, W, Nsup, ent, yhat);

  // 4) per-class gather/select/accumulate/normalize -> wh[Npad, D] f16
  accum_kernel<<<Npad, 256, 0, stream>>>(z, W, C, Nsup, yhat, ent, norms, Kp, wh);

  // 5) output partials: Q[z] = z @ weights^T over K-half z   (512 blocks)
  {
    dim3 grid(B / TM, Npad / TN, 2);
    gemm_f16<<<grid, 256, 0, stream>>>(suph + (size_t)C * D, wh, Q, D, D / 2, pStride2, Npad);
  }

  // 6) out = Q0 + Q1 (valid C cols only)
  reduce_out<<<B, 256, 0, stream>>>(Q, pStride2, Npad, (float*)d_out, C);
}